// Round 5
// baseline (10823.909 us; speedup 1.0000x reference)
//
#include <hip/hip_runtime.h>
#include <hip/hip_bf16.h>

typedef unsigned int u32;
typedef short bf16x8 __attribute__((ext_vector_type(8)));
typedef float floatx4 __attribute__((ext_vector_type(4)));

#define NNODES 50000
#define NEDGES 800000
#define INSZ   1024
#define EMB    500
#define EMBP   512

__device__ __forceinline__ short f2bf(float f) {
    u32 u = __builtin_bit_cast(u32, f);
    u32 r = u + 0x7FFFu + ((u >> 16) & 1u);   // round-to-nearest-even
    return (short)(r >> 16);
}
__device__ __forceinline__ float bf2f(short h) {
    u32 u = ((u32)(unsigned short)h) << 16;
    return __builtin_bit_cast(float, u);
}

#define GLDS16(gp, lp) __builtin_amdgcn_global_load_lds( \
    (const __attribute__((address_space(1))) u32*)(gp),  \
    (__attribute__((address_space(3))) u32*)(lp), 16, 0, 0)

// ---------------------------------------------------------------------------
// Pack fp32 weights -> zero-padded bf16 BT-layout operands.
//   wencP [512][1024] : wenc rows (pad m>=500)
//   Wmid  [512][1024] : k<512 -> conv^T (conv[k][m]), k>=512 -> lin[m][k-512]
//   wdecP [1024][512] : wdec K-padded
// grid covers 524288 threads.
// ---------------------------------------------------------------------------
__global__ void pack_all(const float* __restrict__ wenc, const float* __restrict__ conv,
                         const float* __restrict__ lin,  const float* __restrict__ wdec,
                         short* __restrict__ wencP, short* __restrict__ Wmid,
                         short* __restrict__ wdecP) {
    int tid = blockIdx.x * 256 + threadIdx.x;
    {   // wencP [512][1024]
        int m = tid >> 10, k = tid & 1023;
        wencP[tid] = (m < EMB) ? f2bf(wenc[m * INSZ + k]) : (short)0;
    }
    {   // Wmid [512][1024]
        int m = tid >> 10, k = tid & 1023;
        short v = 0;
        if (m < EMB) {
            if (k < EMBP) { if (k < EMB) v = f2bf(conv[k * EMB + m]); }
            else          { int kk = k - EMBP; if (kk < EMB) v = f2bf(lin[m * EMB + kk]); }
        }
        Wmid[tid] = v;
    }
    {   // wdecP [1024][512]
        int m = tid >> 9, k = tid & 511;
        wdecP[tid] = (k < EMB) ? f2bf(wdec[m * EMB + k]) : (short)0;
    }
}

// ---------------------------------------------------------------------------
// m97-pattern 128x128 MFMA GEMM bodies. 256 thr = 4 waves (2x2 of 64x64),
// BK=32. A-side staging varies per kernel; B staged with global_load_lds.
// C/D layout: col=lane&15, row=(lane>>4)*4+reg.
// ---------------------------------------------------------------------------

// ---- encoder: h[n,m] = sigmoid( sum_k x[n,k]*wencP[m,k] + benc[m] ) -------
__global__ __launch_bounds__(256)
void gemm_enc(const float* __restrict__ X, const short* __restrict__ Wp,
              const float* __restrict__ benc, short* __restrict__ H) {
    __shared__ short As[128 * 32];
    __shared__ short Bs[128 * 32];
    const int tid  = threadIdx.x;
    const int lane = tid & 63;
    const int wave = tid >> 6;
    const int wr   = (wave >> 1) * 64;
    const int wc   = (wave & 1) * 64;
    const int rowBase = blockIdx.y * 128;
    const int colBase = blockIdx.x * 128;

    floatx4 acc[4][4] = {};

    const int r0 = tid >> 2;
    const int c0 = (tid & 3) * 8;
    int ar0 = rowBase + r0;       if (ar0 >= NNODES) ar0 = NNODES - 1;
    int ar1 = rowBase + r0 + 64;  if (ar1 >= NNODES) ar1 = NNODES - 1;
    const float* xP0 = X + (size_t)ar0 * INSZ + c0;
    const float* xP1 = X + (size_t)ar1 * INSZ + c0;
    const short* bP0 = Wp + (size_t)(colBase + r0) * INSZ + c0;
    const short* bP1 = Wp + (size_t)(colBase + r0 + 64) * INSZ + c0;

    const int q8  = (lane >> 4) * 8;
    const int m16 = lane & 15;

    for (int k0 = 0; k0 < INSZ; k0 += 32) {
        {   // fp32 -> bf16 convert-on-stage for A
            floatx4 fa = *(const floatx4*)(xP0 + k0);
            floatx4 fb = *(const floatx4*)(xP0 + k0 + 4);
            floatx4 fc = *(const floatx4*)(xP1 + k0);
            floatx4 fd = *(const floatx4*)(xP1 + k0 + 4);
            bf16x8 p0, p1;
#pragma unroll
            for (int j = 0; j < 4; ++j) {
                p0[j] = f2bf(fa[j]); p0[4 + j] = f2bf(fb[j]);
                p1[j] = f2bf(fc[j]); p1[4 + j] = f2bf(fd[j]);
            }
            *(bf16x8*)&As[tid * 8] = p0;
            *(bf16x8*)&As[2048 + tid * 8] = p1;
        }
        GLDS16(bP0 + k0, &Bs[tid * 8]);
        GLDS16(bP1 + k0, &Bs[2048 + tid * 8]);
        __syncthreads();

        bf16x8 af[4], bfr[4];
#pragma unroll
        for (int i = 0; i < 4; ++i) {
            af[i]  = *(const bf16x8*)&As[(wr + i * 16 + m16) * 32 + q8];
            bfr[i] = *(const bf16x8*)&Bs[(wc + i * 16 + m16) * 32 + q8];
        }
#pragma unroll
        for (int i = 0; i < 4; ++i)
#pragma unroll
            for (int j = 0; j < 4; ++j)
                acc[i][j] = __builtin_amdgcn_mfma_f32_16x16x32_bf16(af[i], bfr[j], acc[i][j], 0, 0, 0);
        __syncthreads();
    }

    const int rq = (lane >> 4) * 4;
#pragma unroll
    for (int i = 0; i < 4; ++i)
#pragma unroll
        for (int j = 0; j < 4; ++j)
#pragma unroll
            for (int reg = 0; reg < 4; ++reg) {
                int row = rowBase + wr + i * 16 + rq + reg;
                int col = colBase + wc + j * 16 + m16;
                if (row < NNODES) {
                    float b = (col < EMB) ? benc[col] : 0.f;
                    float v = 1.f / (1.f + __expf(-(acc[i][j][reg] + b)));
                    H[(size_t)row * EMBP + col] = f2bf(v);
                }
            }
}

// ---- mid: hout[n,m] = sum_{k<512} agg[n,k]*Wmid[m,k]
//                     + sum_{k<512} h[n,k]*Wmid[m,512+k] -----------------
__global__ __launch_bounds__(256)
void gemm_mid(const float* __restrict__ Agg, const short* __restrict__ H,
              const short* __restrict__ Wm, short* __restrict__ Hout) {
    __shared__ short As[128 * 32];
    __shared__ short Bs[128 * 32];
    const int tid  = threadIdx.x;
    const int lane = tid & 63;
    const int wave = tid >> 6;
    const int wr   = (wave >> 1) * 64;
    const int wc   = (wave & 1) * 64;
    const int rowBase = blockIdx.y * 128;
    const int colBase = blockIdx.x * 128;

    floatx4 acc[4][4] = {};

    const int r0 = tid >> 2;
    const int c0 = (tid & 3) * 8;
    int ar0 = rowBase + r0;       if (ar0 >= NNODES) ar0 = NNODES - 1;
    int ar1 = rowBase + r0 + 64;  if (ar1 >= NNODES) ar1 = NNODES - 1;
    const float* agP0 = Agg + (size_t)ar0 * EMBP + c0;
    const float* agP1 = Agg + (size_t)ar1 * EMBP + c0;
    const short* hP0  = H + (size_t)ar0 * EMBP + c0;
    const short* hP1  = H + (size_t)ar1 * EMBP + c0;
    const short* wP0  = Wm + (size_t)(colBase + r0) * 1024 + c0;
    const short* wP1  = Wm + (size_t)(colBase + r0 + 64) * 1024 + c0;

    const int q8  = (lane >> 4) * 8;
    const int m16 = lane & 15;

    for (int k0 = 0; k0 < 1024; k0 += 32) {
        if (k0 < 512) {
            floatx4 fa = *(const floatx4*)(agP0 + k0);
            floatx4 fb = *(const floatx4*)(agP0 + k0 + 4);
            floatx4 fc = *(const floatx4*)(agP1 + k0);
            floatx4 fd = *(const floatx4*)(agP1 + k0 + 4);
            bf16x8 p0, p1;
#pragma unroll
            for (int j = 0; j < 4; ++j) {
                p0[j] = f2bf(fa[j]); p0[4 + j] = f2bf(fb[j]);
                p1[j] = f2bf(fc[j]); p1[4 + j] = f2bf(fd[j]);
            }
            *(bf16x8*)&As[tid * 8] = p0;
            *(bf16x8*)&As[2048 + tid * 8] = p1;
        } else {
            GLDS16(hP0 + (k0 - 512), &As[tid * 8]);
            GLDS16(hP1 + (k0 - 512), &As[2048 + tid * 8]);
        }
        GLDS16(wP0 + k0, &Bs[tid * 8]);
        GLDS16(wP1 + k0, &Bs[2048 + tid * 8]);
        __syncthreads();

        bf16x8 af[4], bfr[4];
#pragma unroll
        for (int i = 0; i < 4; ++i) {
            af[i]  = *(const bf16x8*)&As[(wr + i * 16 + m16) * 32 + q8];
            bfr[i] = *(const bf16x8*)&Bs[(wc + i * 16 + m16) * 32 + q8];
        }
#pragma unroll
        for (int i = 0; i < 4; ++i)
#pragma unroll
            for (int j = 0; j < 4; ++j)
                acc[i][j] = __builtin_amdgcn_mfma_f32_16x16x32_bf16(af[i], bfr[j], acc[i][j], 0, 0, 0);
        __syncthreads();
    }

    const int rq = (lane >> 4) * 4;
#pragma unroll
    for (int i = 0; i < 4; ++i)
#pragma unroll
        for (int j = 0; j < 4; ++j)
#pragma unroll
            for (int reg = 0; reg < 4; ++reg) {
                int row = rowBase + wr + i * 16 + rq + reg;
                int col = colBase + wc + j * 16 + m16;
                if (row < NNODES)
                    Hout[(size_t)row * EMBP + col] = f2bf(acc[i][j][reg]);
            }
}

// ---- decoder: out[n,m] = sum_k hout[n,k]*wdecP[m,k] + bdec[m], fp32 out --
__global__ __launch_bounds__(256)
void gemm_dec(const short* __restrict__ Hout, const short* __restrict__ Wd,
              const float* __restrict__ bdec, float* __restrict__ Out) {
    __shared__ short As[128 * 32];
    __shared__ short Bs[128 * 32];
    const int tid  = threadIdx.x;
    const int lane = tid & 63;
    const int wave = tid >> 6;
    const int wr   = (wave >> 1) * 64;
    const int wc   = (wave & 1) * 64;
    const int rowBase = blockIdx.y * 128;
    const int colBase = blockIdx.x * 128;

    floatx4 acc[4][4] = {};

    const int r0 = tid >> 2;
    const int c0 = (tid & 3) * 8;
    int ar0 = rowBase + r0;       if (ar0 >= NNODES) ar0 = NNODES - 1;
    int ar1 = rowBase + r0 + 64;  if (ar1 >= NNODES) ar1 = NNODES - 1;
    const short* aP0 = Hout + (size_t)ar0 * EMBP + c0;
    const short* aP1 = Hout + (size_t)ar1 * EMBP + c0;
    const short* bP0 = Wd + (size_t)(colBase + r0) * EMBP + c0;
    const short* bP1 = Wd + (size_t)(colBase + r0 + 64) * EMBP + c0;

    const int q8  = (lane >> 4) * 8;
    const int m16 = lane & 15;

    for (int k0 = 0; k0 < EMBP; k0 += 32) {
        GLDS16(aP0 + k0, &As[tid * 8]);
        GLDS16(aP1 + k0, &As[2048 + tid * 8]);
        GLDS16(bP0 + k0, &Bs[tid * 8]);
        GLDS16(bP1 + k0, &Bs[2048 + tid * 8]);
        __syncthreads();

        bf16x8 af[4], bfr[4];
#pragma unroll
        for (int i = 0; i < 4; ++i) {
            af[i]  = *(const bf16x8*)&As[(wr + i * 16 + m16) * 32 + q8];
            bfr[i] = *(const bf16x8*)&Bs[(wc + i * 16 + m16) * 32 + q8];
        }
#pragma unroll
        for (int i = 0; i < 4; ++i)
#pragma unroll
            for (int j = 0; j < 4; ++j)
                acc[i][j] = __builtin_amdgcn_mfma_f32_16x16x32_bf16(af[i], bfr[j], acc[i][j], 0, 0, 0);
        __syncthreads();
    }

    const int rq = (lane >> 4) * 4;
#pragma unroll
    for (int i = 0; i < 4; ++i)
#pragma unroll
        for (int j = 0; j < 4; ++j)
#pragma unroll
            for (int reg = 0; reg < 4; ++reg) {
                int row = rowBase + wr + i * 16 + rq + reg;
                int col = colBase + wc + j * 16 + m16;
                if (row < NNODES)
                    Out[(size_t)row * INSZ + col] = acc[i][j][reg] + bdec[col];
            }
}

// ---------------------------------------------------------------------------
// Edge scatter on h: one wave per edge; lane covers 8 of 512 cols (16B bf16
// load); fp32 atomicAdd into agg[dst] (first half of d_out). cols>=500 skip.
// ---------------------------------------------------------------------------
__global__ __launch_bounds__(256)
void scatter_h(const short* __restrict__ H, const int* __restrict__ src,
               const int* __restrict__ dst, const float* __restrict__ ew,
               float* __restrict__ agg) {
    int e = blockIdx.x * 4 + (threadIdx.x >> 6);
    int lane = threadIdx.x & 63;
    int s = src[e], d = dst[e];
    float w = ew[e];
    bf16x8 v = *(const bf16x8*)(H + (size_t)s * EMBP + lane * 8);
    float* arow = agg + (size_t)d * EMBP + lane * 8;
#pragma unroll
    for (int j = 0; j < 8; ++j) {
        if (lane * 8 + j < EMB) atomicAdd(&arow[j], w * bf2f(v[j]));
    }
}

// ---------------------------------------------------------------------------
extern "C" void kernel_launch(void* const* d_in, const int* in_sizes, int n_in,
                              void* d_out, int out_size, void* d_ws, size_t ws_size,
                              hipStream_t stream) {
    // Reference dtypes: ALL float32 (+ int32 edge_index).
    const float* x    = (const float*)d_in[0];
    const int*   ei   = (const int*)d_in[1];
    const float* ew   = (const float*)d_in[2];
    const float* wenc = (const float*)d_in[3];
    const float* benc = (const float*)d_in[4];
    const float* wdec = (const float*)d_in[5];
    const float* bdec = (const float*)d_in[6];
    const float* conv = (const float*)d_in[7];
    const float* lin  = (const float*)d_in[8];
    float* out = (float*)d_out;   // [50000][1024] fp32 = 204.8 MB

    // ws: wencP 1MB | Wmid 1MB | wdecP 1MB | h 51.2MB | hout 51.2MB  (105.5MB)
    char* ws = (char*)d_ws;
    short* wencP = (short*)(ws);
    short* Wmid  = (short*)(ws + 1048576);
    short* wdecP = (short*)(ws + 2097152);
    short* h     = (short*)(ws + 3145728);
    short* hout  = (short*)(ws + 3145728 + 51200000);

    // agg fp32 [50000][512] = 102.4 MB in the FIRST HALF of d_out; fully
    // consumed by gemm_mid before gemm_dec overwrites d_out (stream order).
    float* agg = (float*)d_out;
    hipMemsetAsync(agg, 0, (size_t)NNODES * EMBP * 4, stream);

    dim3 blk(256);
    pack_all<<<2048, blk, 0, stream>>>(wenc, conv, lin, wdec, wencP, Wmid, wdecP);

    int rowTiles = (NNODES + 127) / 128;   // 391

    // h = sigmoid(x @ wenc^T + benc)
    gemm_enc<<<dim3(EMBP / 128, rowTiles), blk, 0, stream>>>(x, wencP, benc, h);

    // agg[dst] += w * h[src]    (linearity: scatter(h@conv) == scatter(h)@conv)
    scatter_h<<<NEDGES / 4, blk, 0, stream>>>(h, ei, ei + NEDGES, ew, agg);

    // hout = agg @ conv + h @ lin^T   (mixed-A K=1024 against Wmid)
    gemm_mid<<<dim3(EMBP / 128, rowTiles), blk, 0, stream>>>(agg, h, Wmid, hout);

    // out = hout @ wdec^T + bdec      (fp32 store)
    gemm_dec<<<dim3(INSZ / 128, rowTiles), blk, 0, stream>>>(hout, wdecP, bdec, out);
}